// Round 28
// baseline (90.844 us; speedup 1.0000x reference)
//
#include <hip/hip_runtime.h>

typedef __attribute__((ext_vector_type(8))) short short8;
typedef __attribute__((ext_vector_type(4))) float f32x4;

#define T_DIM 4096
#define C_DIM 128
#define U_DIM 256
#define BM 64
#define NROWS 66    // BM + 2 halo rows
#define LDK 136     // padded LDS row stride (bf16 elems)
#define NT 8        // tiles per block (persistent)

__device__ __forceinline__ unsigned short f2bf(float f) {
    unsigned int u = __float_as_uint(f);
    u += 0x7FFFu + ((u >> 16) & 1u);   // round-to-nearest-even
    return (unsigned short)(u >> 16);
}

// Pre-pack w into MFMA fragment order: wfrag[ks][nt][lane][8] bf16,
// where k = ks*32 + (lane>>4)*8 + j, u = nt*16 + (lane&15).
__global__ void prep_kernel(const float* __restrict__ w,
                            const float* __restrict__ b,
                            const float* __restrict__ p,
                            const float* __restrict__ q,
                            unsigned short* __restrict__ wfrag,
                            float* __restrict__ winv,
                            float* __restrict__ p2,
                            float* __restrict__ bc) {
    if (blockIdx.x < 48) {
        int idx = blockIdx.x * 256 + threadIdx.x;   // 0..12287 lane-frags
        int l  = idx & 63;
        int nt = (idx >> 6) & 15;
        int ks = idx >> 10;                         // 0..11
        int n  = nt * 16 + (l & 15);
        int k0 = ks * 32 + ((l >> 4) << 3);
        #pragma unroll
        for (int j = 0; j < 8; ++j) {
            wfrag[(size_t)idx * 8 + j] = f2bf(w[(k0 + j) * U_DIM + n]);
        }
    } else {
        int u = threadIdx.x;                        // 0..255
        float ss = 0.f;
        for (int k = 0; k < 3 * C_DIM; ++k) {
            float v = w[k * U_DIM + u];
            ss += v * v;
        }
        float q2 = q[0] * q[0];
        winv[u] = 1.0f / (sqrtf(fmaxf(ss, 1e-12f)) + q2);
        float pv = p[u];
        p2[u] = pv * pv;
        bc[u] = b[u];
    }
}

// Issue 9 masked float4 loads for tile starting at t0 (rows t0-1 .. t0+64)
#define STAGE_LOAD(t0v, vv)                                                    \
    do {                                                                       \
        _Pragma("unroll")                                                      \
        for (int i_ = 0; i_ < 9; ++i_) {                                       \
            int r_ = r0 + i_ * 8;                                              \
            int t_ = (t0v) + r_ - 1;                                           \
            float4 val_ = make_float4(0.f, 0.f, 0.f, 0.f);                     \
            if (r_ < NROWS && (unsigned)t_ < T_DIM)                            \
                val_ = *(const float4*)(inp + ((size_t)bb * T_DIM + t_) * C_DIM + lc); \
            vv[i_] = val_;                                                     \
        }                                                                      \
    } while (0)

// Reduce + convert + LDS-write previously loaded rows into buffer `buf`
#define STAGE_WRITE(vv, buf)                                                   \
    do {                                                                       \
        _Pragma("unroll")                                                      \
        for (int i_ = 0; i_ < 9; ++i_) {                                       \
            int r_ = r0 + i_ * 8;                                              \
            if (r_ < NROWS) {                                                  \
                float4 val_ = vv[i_];                                          \
                float part_ = val_.x * val_.x + val_.y * val_.y                \
                            + val_.z * val_.z + val_.w * val_.w;               \
                _Pragma("unroll")                                              \
                for (int o_ = 16; o_ > 0; o_ >>= 1)                            \
                    part_ += __shfl_xor(part_, o_, 32);                        \
                if ((tid & 31) == 0) ss_s[buf][r_] = part_;                    \
                ushort4 sv_;                                                   \
                sv_.x = f2bf(val_.x); sv_.y = f2bf(val_.y);                    \
                sv_.z = f2bf(val_.z); sv_.w = f2bf(val_.w);                    \
                *(ushort4*)(&inp_s[buf][r_][lc]) = sv_;                        \
            }                                                                  \
        }                                                                      \
    } while (0)

// 256-thread block = 4 waves, each 64(t) x 16(u); block = 64t x 64u (quarter).
// wr=48 VGPR -> total ~148 regs fits (256,3)'s 170 cap WITHOUT spill:
// 3 independent blocks/CU, 12 waves/CU, full R17 schedule (T14 early loads,
// dbuf LDS, 1 barrier/tile, stores after barrier).
__global__ __launch_bounds__(256, 3) void cossim_main(
        const float* __restrict__ inp,
        const unsigned short* __restrict__ wfrag,
        const float* __restrict__ winv,
        const float* __restrict__ p2g,
        const float* __restrict__ bg,
        const float* __restrict__ qg,
        float* __restrict__ out) {
    __shared__ unsigned short inp_s[2][NROWS][LDK];   // 35.9 KB
    __shared__ float ss_s[2][NROWS];

    const int tid = threadIdx.x;
    int bid = blockIdx.x;
    bid = (bid & 7) * 128 + (bid >> 3);  // XCD-bijective (1024 % 8 == 0):
                                         // uq-siblings adjacent -> same L2
    const int bb = bid >> 5;             // batch (32 work-ids per batch)
    const int tg = (bid >> 2) & 7;       // t-group (512 rows each)
    const int uq = bid & 3;              // u 64-col quarter

    const int wid = tid >> 6;            // 0..3 (16-u tile within quarter)
    const int l   = tid & 63;
    const int l15 = l & 15;
    const int lg  = l >> 4;              // 0..3
    const int r0  = tid >> 5;            // 0..7 (staging row)
    const int lc  = (tid & 31) * 4;      // staging float column
    const int ut  = uq * 4 + wid;        // global 16-u tile index 0..15

    const float q2 = qg[0] * qg[0];
    const short8* wf = (const short8*)wfrag;

    // ---- w-slice in registers (one-time, L2-resident) ----
    short8 wr[12];                       // 48 VGPRs
    #pragma unroll
    for (int ks = 0; ks < 12; ++ks)
        wr[ks] = wf[(size_t)(ks * 16 + ut) * 64 + l];

    const int ucb = ut * 16;
    f32x4 wiv, ppv, bbv;
    {
        int uc = ucb + lg * 4;
        wiv = *(const f32x4*)(winv + uc);
        ppv = *(const f32x4*)(p2g + uc);
        bbv = *(const f32x4*)(bg + uc);
    }

    // ---- prologue: stage tile 0 into buffer 0 ----
    const int tbase = tg * (NT * BM);
    {
        float4 v0[9];
        STAGE_LOAD(tbase, v0);
        STAGE_WRITE(v0, 0);
    }
    __syncthreads();

    int cur = 0;
    for (int it = 0; it < NT; ++it) {
        const int t0 = tbase + it * BM;

        // T14: issue next tile's global loads EARLY (hide HBM under K-loop)
        float4 vn[9];
        if (it + 1 < NT) STAGE_LOAD(t0 + BM, vn);

        // ---- K-loop: pure LDS + MFMA (w from registers) ----
        f32x4 acc[4];                    // 16 AGPRs
        #pragma unroll
        for (int tf = 0; tf < 4; ++tf)
            acc[tf] = (f32x4){0.f, 0.f, 0.f, 0.f};

        #pragma unroll
        for (int ks = 0; ks < 12; ++ks) {
            const int tap = ks >> 2;
            const int c0  = (ks & 3) * 32 + lg * 8;
            short8 xv[4];
            #pragma unroll
            for (int tf = 0; tf < 4; ++tf)
                xv[tf] = *(const short8*)(&inp_s[cur][tf * 16 + l15 + tap][c0]);
            #pragma unroll
            for (int tf = 0; tf < 4; ++tf)
                acc[tf] = __builtin_amdgcn_mfma_f32_16x16x32_bf16(
                    wr[ks], xv[tf], acc[tf], 0, 0, 0);
        }

        // ---- xi from current ss buffer (before it can be reused) ----
        float xi[4];
        #pragma unroll
        for (int tf = 0; tf < 4; ++tf) {
            int trow = tf * 16 + l15;
            float s3 = ss_s[cur][trow] + ss_s[cur][trow + 1] + ss_s[cur][trow + 2];
            xi[tf] = 1.0f / (sqrtf(fmaxf(s3, 1e-12f)) + q2);
        }

        // ---- stage next tile into the OTHER buffer (no read conflict) ----
        if (it + 1 < NT) STAGE_WRITE(vn, cur ^ 1);
        __syncthreads();   // single barrier per tile

        // ---- epilogue AFTER barrier: stores drain under next K-loop ----
        #pragma unroll
        for (int tf = 0; tf < 4; ++tf) {
            float* orow = out + ((size_t)bb * T_DIM + t0 + tf * 16 + l15) * U_DIM;
            f32x4 r;
            #pragma unroll
            for (int j = 0; j < 4; ++j) {
                float raw = acc[tf][j];
                float y   = raw * xi[tf] * wiv[j];
                float ay  = fabsf(y) + 1e-12f;
                float pw  = ppv[j];
                float rr  = (pw == 1.0f) ? ay : exp2f(pw * __log2f(ay));
                r[j] = __builtin_copysignf(rr, raw) + bbv[j];
            }
            *(f32x4*)(orow + ucb + lg * 4) = r;
        }

        cur ^= 1;
    }
}

extern "C" void kernel_launch(void* const* d_in, const int* in_sizes, int n_in,
                              void* d_out, int out_size, void* d_ws, size_t ws_size,
                              hipStream_t stream) {
    const float* inp = (const float*)d_in[0];
    const float* w   = (const float*)d_in[1];
    const float* b   = (const float*)d_in[2];
    const float* p   = (const float*)d_in[3];
    const float* q   = (const float*)d_in[4];
    float* out = (float*)d_out;

    unsigned short* wfrag = (unsigned short*)d_ws;            // 196608 B
    float* winv = (float*)((char*)d_ws + 196608);
    float* p2   = winv + 256;
    float* bc   = p2 + 256;

    prep_kernel<<<49, 256, 0, stream>>>(w, b, p, q, wfrag, winv, p2, bc);
    cossim_main<<<1024, 256, 0, stream>>>(inp, wfrag, winv, p2, bc, q, out);
}

// Round 29
// 63.154 us; speedup vs baseline: 1.4384x; 1.4384x over previous
//
#include <hip/hip_runtime.h>

typedef __attribute__((ext_vector_type(8))) short short8;
typedef __attribute__((ext_vector_type(4))) float f32x4;

#define T_DIM 4096
#define C_DIM 128
#define U_DIM 256
#define BM 64
#define NROWS 66    // BM + 2 halo rows
#define LDK 136     // padded LDS row stride (bf16 elems)
#define NT 8        // tiles per block (persistent)

__device__ __forceinline__ unsigned short f2bf(float f) {
    unsigned int u = __float_as_uint(f);
    u += 0x7FFFu + ((u >> 16) & 1u);   // round-to-nearest-even
    return (unsigned short)(u >> 16);
}

// Pre-pack w into MFMA fragment order: wfrag[ks][nt][lane][8] bf16,
// where k = ks*32 + (lane>>4)*8 + j, u = nt*16 + (lane&15).
__global__ void prep_kernel(const float* __restrict__ w,
                            const float* __restrict__ b,
                            const float* __restrict__ p,
                            const float* __restrict__ q,
                            unsigned short* __restrict__ wfrag,
                            float* __restrict__ winv,
                            float* __restrict__ p2,
                            float* __restrict__ bc) {
    if (blockIdx.x < 48) {
        int idx = blockIdx.x * 256 + threadIdx.x;   // 0..12287 lane-frags
        int l  = idx & 63;
        int nt = (idx >> 6) & 15;
        int ks = idx >> 10;                         // 0..11
        int n  = nt * 16 + (l & 15);
        int k0 = ks * 32 + ((l >> 4) << 3);
        #pragma unroll
        for (int j = 0; j < 8; ++j) {
            wfrag[(size_t)idx * 8 + j] = f2bf(w[(k0 + j) * U_DIM + n]);
        }
    } else {
        int u = threadIdx.x;                        // 0..255
        float ss = 0.f;
        for (int k = 0; k < 3 * C_DIM; ++k) {
            float v = w[k * U_DIM + u];
            ss += v * v;
        }
        float q2 = q[0] * q[0];
        winv[u] = 1.0f / (sqrtf(fmaxf(ss, 1e-12f)) + q2);
        float pv = p[u];
        p2[u] = pv * pv;
        bc[u] = b[u];
    }
}

// Issue 9 masked float4 loads for tile starting at t0 (rows t0-1 .. t0+64)
#define STAGE_LOAD(t0v, vv)                                                    \
    do {                                                                       \
        _Pragma("unroll")                                                      \
        for (int i_ = 0; i_ < 9; ++i_) {                                       \
            int r_ = r0 + i_ * 8;                                              \
            int t_ = (t0v) + r_ - 1;                                           \
            float4 val_ = make_float4(0.f, 0.f, 0.f, 0.f);                     \
            if (r_ < NROWS && (unsigned)t_ < T_DIM)                            \
                val_ = *(const float4*)(inp + ((size_t)bb * T_DIM + t_) * C_DIM + lc); \
            vv[i_] = val_;                                                     \
        }                                                                      \
    } while (0)

// Reduce + convert + LDS-write previously loaded rows into buffer `buf`
#define STAGE_WRITE(vv, buf)                                                   \
    do {                                                                       \
        _Pragma("unroll")                                                      \
        for (int i_ = 0; i_ < 9; ++i_) {                                       \
            int r_ = r0 + i_ * 8;                                              \
            if (r_ < NROWS) {                                                  \
                float4 val_ = vv[i_];                                          \
                float part_ = val_.x * val_.x + val_.y * val_.y                \
                            + val_.z * val_.z + val_.w * val_.w;               \
                _Pragma("unroll")                                              \
                for (int o_ = 16; o_ > 0; o_ >>= 1)                            \
                    part_ += __shfl_xor(part_, o_, 32);                        \
                if ((tid & 31) == 0) ss_s[buf][r_] = part_;                    \
                ushort4 sv_;                                                   \
                sv_.x = f2bf(val_.x); sv_.y = f2bf(val_.y);                    \
                sv_.z = f2bf(val_.z); sv_.w = f2bf(val_.w);                    \
                *(ushort4*)(&inp_s[buf][r_][lc]) = sv_;                        \
            }                                                                  \
        }                                                                      \
    } while (0)

// w-in-registers persistent main, double-buffered LDS, 1 barrier/tile,
// stores issued AFTER the barrier so they drain under the next K-loop.
__global__ __launch_bounds__(256, 2) void cossim_main(
        const float* __restrict__ inp,
        const unsigned short* __restrict__ wfrag,
        const float* __restrict__ winv,
        const float* __restrict__ p2g,
        const float* __restrict__ bg,
        const float* __restrict__ qg,
        float* __restrict__ out) {
    __shared__ unsigned short inp_s[2][NROWS][LDK];   // 35.9 KB
    __shared__ float ss_s[2][NROWS];

    const int tid = threadIdx.x;
    int bid = blockIdx.x;
    bid = (bid & 7) * 64 + (bid >> 3);   // XCD-bijective (512 % 8 == 0)
    const int bb = bid >> 4;             // batch (16 work-ids per batch)
    const int tg = (bid >> 1) & 7;       // t-group (512 rows each)
    const int uh = bid & 1;              // u 128-col half

    const int wid = tid >> 6;            // 0..3 (u 32-col slice within half)
    const int l   = tid & 63;
    const int l15 = l & 15;
    const int lg  = l >> 4;              // 0..3
    const int r0  = tid >> 5;            // 0..7 (staging row)
    const int lc  = (tid & 31) * 4;      // staging float column

    const float q2 = qg[0] * qg[0];
    const short8* wf = (const short8*)wfrag;

    // ---- load this wave's w-slice into registers (one-time, L2-resident) ----
    short8 wr[12][2];                    // 96 VGPRs
    #pragma unroll
    for (int ks = 0; ks < 12; ++ks)
        #pragma unroll
        for (int uf = 0; uf < 2; ++uf)
            wr[ks][uf] = wf[(size_t)(ks * 16 + uh * 8 + wid * 2 + uf) * 64 + l];

    const int ucb = uh * 128 + wid * 32;
    f32x4 wiv[2], ppv[2], bbv[2];
    #pragma unroll
    for (int uf = 0; uf < 2; ++uf) {
        int uc = ucb + uf * 16 + lg * 4;
        wiv[uf] = *(const f32x4*)(winv + uc);
        ppv[uf] = *(const f32x4*)(p2g + uc);
        bbv[uf] = *(const f32x4*)(bg + uc);
    }

    // ---- prologue: stage tile 0 into buffer 0 ----
    const int tbase = tg * (NT * BM);
    {
        float4 v0[9];
        STAGE_LOAD(tbase, v0);
        STAGE_WRITE(v0, 0);
    }
    __syncthreads();

    int cur = 0;
    for (int it = 0; it < NT; ++it) {
        const int t0 = tbase + it * BM;

        // T14: issue next tile's global loads EARLY (hide HBM under K-loop)
        float4 vn[9];
        if (it + 1 < NT) STAGE_LOAD(t0 + BM, vn);

        // ---- K-loop: pure LDS + MFMA (w from registers) ----
        f32x4 acc[4][2];
        #pragma unroll
        for (int tf = 0; tf < 4; ++tf)
            #pragma unroll
            for (int uf = 0; uf < 2; ++uf)
                acc[tf][uf] = (f32x4){0.f, 0.f, 0.f, 0.f};

        #pragma unroll
        for (int ks = 0; ks < 12; ++ks) {
            const int tap = ks >> 2;
            const int c0  = (ks & 3) * 32 + lg * 8;
            short8 xv[4];
            #pragma unroll
            for (int tf = 0; tf < 4; ++tf)
                xv[tf] = *(const short8*)(&inp_s[cur][tf * 16 + l15 + tap][c0]);
            #pragma unroll
            for (int tf = 0; tf < 4; ++tf)
                #pragma unroll
                for (int uf = 0; uf < 2; ++uf)
                    acc[tf][uf] = __builtin_amdgcn_mfma_f32_16x16x32_bf16(
                        wr[ks][uf], xv[tf], acc[tf][uf], 0, 0, 0);
        }

        // ---- xi from current ss buffer (before it can be reused) ----
        float xi[4];
        #pragma unroll
        for (int tf = 0; tf < 4; ++tf) {
            int trow = tf * 16 + l15;
            float s3 = ss_s[cur][trow] + ss_s[cur][trow + 1] + ss_s[cur][trow + 2];
            xi[tf] = 1.0f / (sqrtf(fmaxf(s3, 1e-12f)) + q2);
        }

        // ---- stage next tile into the OTHER buffer (no read conflict) ----
        if (it + 1 < NT) STAGE_WRITE(vn, cur ^ 1);
        __syncthreads();   // single barrier per tile

        // ---- epilogue AFTER barrier: stores drain under next K-loop ----
        #pragma unroll
        for (int tf = 0; tf < 4; ++tf) {
            float* orow = out + ((size_t)bb * T_DIM + t0 + tf * 16 + l15) * U_DIM;
            #pragma unroll
            for (int uf = 0; uf < 2; ++uf) {
                f32x4 r;
                #pragma unroll
                for (int j = 0; j < 4; ++j) {
                    float raw = acc[tf][uf][j];
                    float y   = raw * xi[tf] * wiv[uf][j];
                    float ay  = fabsf(y) + 1e-12f;
                    float pw  = ppv[uf][j];
                    float rr  = (pw == 1.0f) ? ay : exp2f(pw * __log2f(ay));
                    r[j] = __builtin_copysignf(rr, raw) + bbv[uf][j];
                }
                *(f32x4*)(orow + ucb + uf * 16 + lg * 4) = r;
            }
        }

        cur ^= 1;
    }
}

extern "C" void kernel_launch(void* const* d_in, const int* in_sizes, int n_in,
                              void* d_out, int out_size, void* d_ws, size_t ws_size,
                              hipStream_t stream) {
    const float* inp = (const float*)d_in[0];
    const float* w   = (const float*)d_in[1];
    const float* b   = (const float*)d_in[2];
    const float* p   = (const float*)d_in[3];
    const float* q   = (const float*)d_in[4];
    float* out = (float*)d_out;

    unsigned short* wfrag = (unsigned short*)d_ws;            // 196608 B
    float* winv = (float*)((char*)d_ws + 196608);
    float* p2   = winv + 256;
    float* bc   = p2 + 256;

    prep_kernel<<<49, 256, 0, stream>>>(w, b, p, q, wfrag, winv, p2, bc);
    cossim_main<<<512, 256, 0, stream>>>(inp, wfrag, winv, p2, bc, q, out);
}